// Round 1
// baseline (3048.466 us; speedup 1.0000x reference)
//
#include <hip/hip_runtime.h>
#include <hip/hip_bf16.h>

// Problem dims (derived at launch from in_sizes, but sized for):
//   b=2048, m=8192, d=1024, 2d=2048, out=1000, all fp32.

#define TPB 256

__device__ __forceinline__ float block_reduce_sum(float v, float* sred) {
    // wave-64 shuffle reduce, then cross-wave via LDS
    #pragma unroll
    for (int off = 32; off > 0; off >>= 1) v += __shfl_down(v, off, 64);
    int lane = threadIdx.x & 63;
    int wid  = threadIdx.x >> 6;
    if (lane == 0) sred[wid] = v;
    __syncthreads();
    if (threadIdx.x == 0) {
        float s = 0.f;
        int nw = blockDim.x >> 6;
        for (int i = 0; i < nw; ++i) s += sred[i];
        sred[0] = s;
    }
    __syncthreads();
    float r = sred[0];
    __syncthreads();   // allow immediate reuse of sred
    return r;
}

// One block per row: y = x / sqrt(sum(x^2) + 1e-6)
__global__ __launch_bounds__(TPB) void normalize_rows(const float* __restrict__ X,
                                                      float* __restrict__ Y, int cols) {
    __shared__ float sred[8];
    int row = blockIdx.x, tid = threadIdx.x;
    const float4* x4 = (const float4*)(X + (size_t)row * cols);
    float4*       y4 = (float4*)(Y + (size_t)row * cols);
    int n4 = cols >> 2;
    float ss = 0.f;
    for (int i = tid; i < n4; i += TPB) {
        float4 v = x4[i];
        ss += v.x * v.x + v.y * v.y + v.z * v.z + v.w * v.w;
    }
    float tot = block_reduce_sum(ss, sred);
    float inv = 1.0f / sqrtf(tot + 1e-6f);
    for (int i = tid; i < n4; i += TPB) {
        float4 v = x4[i];
        v.x *= inv; v.y *= inv; v.z *= inv; v.w *= inv;
        y4[i] = v;
    }
}

// In-place sparsemax along rows of Z [rows x m], m <= 8192, m % 4 == 0.
// Michelot's algorithm: exact projection onto simplex without sorting.
__global__ __launch_bounds__(TPB) void sparsemax_rows(float* __restrict__ Z, int m) {
    __shared__ float sz[8192];
    __shared__ float sred[8];
    int row = blockIdx.x, tid = threadIdx.x;
    float* zrow = Z + (size_t)row * m;
    int n4 = m >> 2;
    float4* sz4 = (float4*)sz;
    const float4* zr4 = (const float4*)zrow;
    for (int i = tid; i < n4; i += TPB) sz4[i] = zr4[i];
    __syncthreads();

    // initial tau with full support
    float ps = 0.f;
    for (int i = tid; i < m; i += TPB) ps += sz[i];
    float tot = block_reduce_sum(ps, sred);
    float tau = (tot - 1.0f) / (float)m;
    float prev_cnt = (float)m;

    for (int it = 0; it < 64; ++it) {
        float s = 0.f, c = 0.f;
        for (int i = tid; i < m; i += TPB) {
            float z = sz[i];
            if (z > tau) { s += z; c += 1.0f; }
        }
        s = block_reduce_sum(s, sred);
        c = block_reduce_sum(c, sred);
        if (c < 0.5f) break;            // degenerate guard
        if (c == prev_cnt) break;       // fixed point -> exact tau
        tau = (s - 1.0f) / c;
        prev_cnt = c;
    }

    for (int i = tid; i < n4; i += TPB) {
        float4 v = sz4[i];
        v.x = fmaxf(v.x - tau, 0.f);
        v.y = fmaxf(v.y - tau, 0.f);
        v.z = fmaxf(v.z - tau, 0.f);
        v.w = fmaxf(v.w - tau, 0.f);
        ((float4*)zrow)[i] = v;
    }
}

// C[M,N] = A[M,K] * B  (+bias)(+relu).  TRANSB: B is [N,K] (C=A*B^T) else [K,N].
// 64x64 block tile, BK=16, 256 threads, 4x4 per thread.
// Requires M % 64 == 0, K % 16 == 0. N guarded.
template <int TRANSB, int RELU, int HASBIAS>
__global__ __launch_bounds__(TPB) void gemm64(const float* __restrict__ A,
                                              const float* __restrict__ B,
                                              const float* __restrict__ bias,
                                              float* __restrict__ C,
                                              int M, int N, int K) {
    __shared__ float As[16][65];
    __shared__ float Bs[16][65];
    int tid = threadIdx.x;
    int tx = tid & 15, ty = tid >> 4;
    int rowBase = blockIdx.y * 64;
    int colBase = blockIdx.x * 64;

    float acc[4][4] = {};

    for (int k0 = 0; k0 < K; k0 += 16) {
        for (int l = tid; l < 1024; l += TPB) {
            int ar = l >> 4, ak = l & 15;
            As[ak][ar] = A[(size_t)(rowBase + ar) * K + k0 + ak];
        }
        if (TRANSB) {
            for (int l = tid; l < 1024; l += TPB) {
                int bn = l >> 4, bk = l & 15;
                int n = colBase + bn;
                Bs[bk][bn] = (n < N) ? B[(size_t)n * K + k0 + bk] : 0.0f;
            }
        } else {
            for (int l = tid; l < 1024; l += TPB) {
                int bk = l >> 6, bn = l & 63;
                int n = colBase + bn;
                Bs[bk][bn] = (n < N) ? B[(size_t)(k0 + bk) * N + n] : 0.0f;
            }
        }
        __syncthreads();
        #pragma unroll
        for (int k = 0; k < 16; ++k) {
            float a[4], bv[4];
            #pragma unroll
            for (int i = 0; i < 4; ++i) a[i] = As[k][ty * 4 + i];
            #pragma unroll
            for (int j = 0; j < 4; ++j) bv[j] = Bs[k][tx * 4 + j];
            #pragma unroll
            for (int i = 0; i < 4; ++i)
                #pragma unroll
                for (int j = 0; j < 4; ++j) acc[i][j] += a[i] * bv[j];
        }
        __syncthreads();
    }

    #pragma unroll
    for (int i = 0; i < 4; ++i) {
        int r = rowBase + ty * 4 + i;
        #pragma unroll
        for (int j = 0; j < 4; ++j) {
            int c = colBase + tx * 4 + j;
            if (c < N) {
                float v = acc[i][j];
                if (HASBIAS) v += bias[c];
                if (RELU) v = fmaxf(v, 0.f);
                C[(size_t)r * N + c] = v;
            }
        }
    }
}

extern "C" void kernel_launch(void* const* d_in, const int* in_sizes, int n_in,
                              void* d_out, int out_size, void* d_ws, size_t ws_size,
                              hipStream_t stream) {
    const float* enc = (const float*)d_in[0];   // [b, d]
    const float* mem = (const float*)d_in[1];   // [m, d]
    const float* W1  = (const float*)d_in[2];   // [d, 2d]
    const float* b1  = (const float*)d_in[3];   // [2d]
    const float* W2  = (const float*)d_in[4];   // [2d, out]
    const float* b2  = (const float*)d_in[5];   // [out]

    const int d    = in_sizes[3] / 2;           // 1024
    const int b    = in_sizes[0] / d;           // 2048
    const int m    = in_sizes[1] / d;           // 8192
    const int d2   = in_sizes[3];               // 2048
    const int outN = in_sizes[5];               // 1000

    float* ws = (float*)d_ws;
    float* xn = ws;                              // b*d
    float* yn = xn + (size_t)b * d;              // m*d
    float* Z  = yn + (size_t)m * d;              // b*m  (cos sim -> sparsemax weights)
    float* mv = Z  + (size_t)b * m;              // b*d
    float* h  = mv + (size_t)b * d;              // b*d2

    normalize_rows<<<b, TPB, 0, stream>>>(enc, xn, d);
    normalize_rows<<<m, TPB, 0, stream>>>(mem, yn, d);

    // Z = xn * yn^T  (cosine similarity; sparsemax(-dist) == sparsemax(cos) by shift invariance)
    gemm64<1, 0, 0><<<dim3(m / 64, b / 64), TPB, 0, stream>>>(xn, yn, nullptr, Z, b, m, d);

    sparsemax_rows<<<b, TPB, 0, stream>>>(Z, m);

    // mv = Z * mem   [b,m] x [m,d]
    gemm64<0, 0, 0><<<dim3(d / 64, b / 64), TPB, 0, stream>>>(Z, mem, nullptr, mv, b, d, m);

    // h = relu(mv * W1 + b1)   [b,d] x [d,2d]
    gemm64<0, 1, 1><<<dim3(d2 / 64, b / 64), TPB, 0, stream>>>(mv, W1, b1, h, b, d2, d);

    // out = h * W2 + b2   [b,2d] x [2d,out]
    gemm64<0, 0, 1><<<dim3((outN + 63) / 64, b / 64), TPB, 0, stream>>>(h, W2, b2,
                                                                        (float*)d_out, b, outN, d2);
}

// Round 2
// 485.993 us; speedup vs baseline: 6.2727x; 6.2727x over previous
//
#include <hip/hip_runtime.h>
#include <hip/hip_bf16.h>

// b=2048, m=8192, d=1024, 2d=2048, out=1000. fp32 in/out, bf16 MFMA GEMMs.

#define TPB 256

typedef __bf16 bf16x8 __attribute__((ext_vector_type(8)));
typedef float  f32x4  __attribute__((ext_vector_type(4)));

typedef const __attribute__((address_space(1))) void* gas_ptr;
typedef __attribute__((address_space(3))) void*       las_ptr;

__device__ __forceinline__ unsigned short f2bf(float f) {
    __hip_bfloat16 h = __float2bfloat16(f);
    union { __hip_bfloat16 h; unsigned short s; } u; u.h = h; return u.s;
}

__device__ __forceinline__ float block_reduce_sum(float v, float* sred) {
    #pragma unroll
    for (int off = 32; off > 0; off >>= 1) v += __shfl_down(v, off, 64);
    int lane = threadIdx.x & 63;
    int wid  = threadIdx.x >> 6;
    if (lane == 0) sred[wid] = v;
    __syncthreads();
    if (threadIdx.x == 0) {
        float s = 0.f;
        for (int i = 0; i < 4; ++i) s += sred[i];
        sred[0] = s;
    }
    __syncthreads();
    float r = sred[0];
    __syncthreads();
    return r;
}

// One block per row: y_bf16 = x / sqrt(sum(x^2) + 1e-6)
__global__ __launch_bounds__(TPB) void normalize_rows_bf16(const float* __restrict__ X,
                                                           unsigned short* __restrict__ Y,
                                                           int cols) {
    __shared__ float sred[4];
    int row = blockIdx.x, tid = threadIdx.x;
    const float4* x4 = (const float4*)(X + (size_t)row * cols);
    ushort4* y4 = (ushort4*)(Y + (size_t)row * cols);
    int n4 = cols >> 2;
    float ss = 0.f;
    for (int i = tid; i < n4; i += TPB) {
        float4 v = x4[i];
        ss += v.x * v.x + v.y * v.y + v.z * v.z + v.w * v.w;
    }
    float tot = block_reduce_sum(ss, sred);
    float inv = 1.0f / sqrtf(tot + 1e-6f);
    for (int i = tid; i < n4; i += TPB) {
        float4 v = x4[i];
        ushort4 o;
        o.x = f2bf(v.x * inv); o.y = f2bf(v.y * inv);
        o.z = f2bf(v.z * inv); o.w = f2bf(v.w * inv);
        y4[i] = o;
    }
}

// Transpose + cast: in fp32 [R][C] -> out bf16 [Cpad][R]; rows c in [C, Cpad) are zero.
// R % 32 == 0. grid = (Cpad/32, R/32), 256 threads.
__global__ __launch_bounds__(TPB) void transpose_cast(const float* __restrict__ in,
                                                      unsigned short* __restrict__ out,
                                                      int R, int C, int Cpad) {
    __shared__ float t[32][33];
    int x = threadIdx.x & 31, y = threadIdx.x >> 5;  // y in 0..7
    int r0 = blockIdx.y * 32, c0 = blockIdx.x * 32;
    #pragma unroll
    for (int yy = y; yy < 32; yy += 8) {
        int c = c0 + x;
        t[yy][x] = (c < C) ? in[(size_t)(r0 + yy) * C + c] : 0.f;
    }
    __syncthreads();
    #pragma unroll
    for (int yy = y; yy < 32; yy += 8) {
        int c = c0 + yy;
        if (c < Cpad)
            out[(size_t)c * R + r0 + x] = f2bf(t[x][yy]);
    }
}

// In-place sparsemax: read fp32 row of Z [rows][m], write bf16 row (pitch outPitch shorts).
// Michelot fixed-point projection (exact, sort-free). m <= 8192.
__global__ __launch_bounds__(TPB) void sparsemax_rows_bf16(const float* __restrict__ Z,
                                                           unsigned short* __restrict__ W,
                                                           int m, int outPitch) {
    __shared__ float sz[8192];
    __shared__ float sred[4];
    int row = blockIdx.x, tid = threadIdx.x;
    const float4* zr4 = (const float4*)(Z + (size_t)row * m);
    int n4 = m >> 2;
    float4* sz4 = (float4*)sz;
    for (int i = tid; i < n4; i += TPB) sz4[i] = zr4[i];
    __syncthreads();

    float ps = 0.f;
    for (int i = tid; i < m; i += TPB) ps += sz[i];
    float tot = block_reduce_sum(ps, sred);
    float tau = (tot - 1.0f) / (float)m;
    float prev_cnt = (float)m;

    for (int it = 0; it < 64; ++it) {
        float s = 0.f, c = 0.f;
        for (int i = tid; i < m; i += TPB) {
            float z = sz[i];
            if (z > tau) { s += z; c += 1.0f; }
        }
        s = block_reduce_sum(s, sred);
        c = block_reduce_sum(c, sred);
        if (c < 0.5f) break;
        if (c == prev_cnt) break;
        tau = (s - 1.0f) / c;
        prev_cnt = c;
    }

    ushort4* w4 = (ushort4*)(W + (size_t)row * outPitch);
    for (int i = tid; i < n4; i += TPB) {
        float4 v = sz4[i];
        ushort4 o;
        o.x = f2bf(fmaxf(v.x - tau, 0.f));
        o.y = f2bf(fmaxf(v.y - tau, 0.f));
        o.z = f2bf(fmaxf(v.z - tau, 0.f));
        o.w = f2bf(fmaxf(v.w - tau, 0.f));
        w4[i] = o;
    }
}

// C[M][ldc] = A[M][lda(bf16)] * B^T  (+bias)(+relu).  B is [Npad][K] bf16 row-major.
// 128x128 tile, BK=32, 256 threads = 4 waves (2x2), mfma_f32_16x16x32_bf16.
// M % 128 == 0, Npad % 128 == 0, K % 32 == 0. Store guard: col < NOUT.
template <int STORE_BF16, int RELU, int HASBIAS>
__global__ __launch_bounds__(TPB) void gemm_bt(const unsigned short* __restrict__ A,
                                               const unsigned short* __restrict__ B,
                                               const float* __restrict__ bias,
                                               void* __restrict__ C,
                                               int M, int K, int lda, int NOUT, int ldc) {
    __shared__ unsigned short lA[128 * 32];
    __shared__ unsigned short lB[128 * 32];
    int tid = threadIdx.x;
    int lane = tid & 63, wv = tid >> 6;
    int wm = (wv & 1) * 64, wn = (wv >> 1) * 64;
    int lr = lane & 15, kq = lane >> 4;

    int rowBase = blockIdx.y * 128;
    int colBase = blockIdx.x * 128;

    f32x4 acc[4][4] = {};

    for (int k0 = 0; k0 < K; k0 += 32) {
        #pragma unroll
        for (int l = 0; l < 2; ++l) {
            int li = l * 256 + tid;
            int row = li >> 2, seg = li & 3;
            const char* g = (const char*)(A + (size_t)(rowBase + row) * lda + k0) + seg * 16;
            __builtin_amdgcn_global_load_lds((gas_ptr)g, (las_ptr)((char*)lA + li * 16), 16, 0, 0);
        }
        #pragma unroll
        for (int l = 0; l < 2; ++l) {
            int li = l * 256 + tid;
            int row = li >> 2, seg = li & 3;
            const char* g = (const char*)(B + (size_t)(colBase + row) * K + k0) + seg * 16;
            __builtin_amdgcn_global_load_lds((gas_ptr)g, (las_ptr)((char*)lB + li * 16), 16, 0, 0);
        }
        __syncthreads();

        bf16x8 av[4], bv[4];
        #pragma unroll
        for (int i = 0; i < 4; ++i)
            av[i] = *(const bf16x8*)&lA[(wm + i * 16 + lr) * 32 + kq * 8];
        #pragma unroll
        for (int j = 0; j < 4; ++j)
            bv[j] = *(const bf16x8*)&lB[(wn + j * 16 + lr) * 32 + kq * 8];
        #pragma unroll
        for (int i = 0; i < 4; ++i)
            #pragma unroll
            for (int j = 0; j < 4; ++j)
                acc[i][j] = __builtin_amdgcn_mfma_f32_16x16x32_bf16(av[i], bv[j], acc[i][j], 0, 0, 0);
        __syncthreads();
    }

    float* Cf = (float*)C;
    unsigned short* Cb = (unsigned short*)C;
    #pragma unroll
    for (int j = 0; j < 4; ++j) {
        int col = colBase + wn + j * 16 + lr;
        if (col >= NOUT) continue;
        float bv_ = HASBIAS ? bias[col] : 0.f;
        #pragma unroll
        for (int i = 0; i < 4; ++i) {
            #pragma unroll
            for (int r = 0; r < 4; ++r) {
                int row = rowBase + wm + i * 16 + kq * 4 + r;
                float v = acc[i][j][r] + bv_;
                if (RELU) v = fmaxf(v, 0.f);
                if (STORE_BF16) Cb[(size_t)row * ldc + col] = f2bf(v);
                else            Cf[(size_t)row * ldc + col] = v;
            }
        }
    }
}

extern "C" void kernel_launch(void* const* d_in, const int* in_sizes, int n_in,
                              void* d_out, int out_size, void* d_ws, size_t ws_size,
                              hipStream_t stream) {
    const float* enc = (const float*)d_in[0];   // [b, d]
    const float* mem = (const float*)d_in[1];   // [m, d]
    const float* W1  = (const float*)d_in[2];   // [d, 2d]
    const float* b1  = (const float*)d_in[3];   // [2d]
    const float* W2  = (const float*)d_in[4];   // [2d, out]
    const float* b2  = (const float*)d_in[5];   // [out]

    const int d    = in_sizes[3] / 2;           // 1024
    const int b    = in_sizes[0] / d;           // 2048
    const int m    = in_sizes[1] / d;           // 8192
    const int d2   = in_sizes[3];               // 2048
    const int outN = in_sizes[5];               // 1000
    const int outPad = 1024;

    unsigned short* xn   = (unsigned short*)d_ws;                     // [b][d] bf16
    unsigned short* yn   = xn  + (size_t)b * d;                       // [m][d] bf16
    unsigned short* memT = yn  + (size_t)m * d;                       // [d][m] bf16
    unsigned short* W1T  = memT + (size_t)d * m;                      // [2d][d] bf16
    unsigned short* W2T  = W1T + (size_t)d2 * d;                      // [outPad][2d] bf16
    float*          Z    = (float*)(W2T + (size_t)outPad * d2);       // [b][m] fp32
    unsigned short* Wb   = (unsigned short*)Z;                        // bf16 overlay, pitch 2m
    unsigned short* mv   = (unsigned short*)(Z + (size_t)b * m);      // [b][d] bf16
    unsigned short* h    = mv + (size_t)b * d;                        // [b][2d] bf16

    normalize_rows_bf16<<<b, TPB, 0, stream>>>(enc, xn, d);
    normalize_rows_bf16<<<m, TPB, 0, stream>>>(mem, yn, d);

    // mem [m][d] -> memT [d][m]
    transpose_cast<<<dim3(d / 32, m / 32), TPB, 0, stream>>>(mem, memT, m, d, d);
    // W1 [d][2d] -> W1T [2d][d]
    transpose_cast<<<dim3(d2 / 32, d / 32), TPB, 0, stream>>>(W1, W1T, d, d2, d2);
    // W2 [2d][outN] -> W2T [outPad][2d], zero-padded
    transpose_cast<<<dim3(outPad / 32, d2 / 32), TPB, 0, stream>>>(W2, W2T, d2, outN, outPad);

    // Z = xn * yn^T   [b][m] fp32  (cosine similarity; sparsemax is shift-invariant)
    gemm_bt<0, 0, 0><<<dim3(m / 128, b / 128), TPB, 0, stream>>>(xn, yn, nullptr, Z,
                                                                 b, d, d, m, m);
    // sparsemax rows -> bf16 overlay (pitch 2m shorts)
    sparsemax_rows_bf16<<<b, TPB, 0, stream>>>(Z, Wb, m, 2 * m);

    // mv = W * mem   [b][d] bf16
    gemm_bt<1, 0, 0><<<dim3(d / 128, b / 128), TPB, 0, stream>>>(Wb, memT, nullptr, mv,
                                                                 b, m, 2 * m, d, d);
    // h = relu(mv * W1 + b1)   [b][2d] bf16
    gemm_bt<1, 1, 1><<<dim3(d2 / 128, b / 128), TPB, 0, stream>>>(mv, W1T, b1, h,
                                                                  b, d, d, d2, d2);
    // out = h * W2 + b2   [b][outN] fp32
    gemm_bt<0, 0, 1><<<dim3(outPad / 128, b / 128), TPB, 0, stream>>>(h, W2T, b2, d_out,
                                                                      b, d2, d2, outN, outN);
}

// Round 3
// 337.182 us; speedup vs baseline: 9.0410x; 1.4413x over previous
//
#include <hip/hip_runtime.h>
#include <hip/hip_bf16.h>

// b=2048, m=8192, d=1024, 2d=2048, out=1000. fp32 in/out, bf16 MFMA GEMMs.
// mv = sparsemax(Z) @ mem exploits sparsemax support sparsity (~100/8192):
// compact (idx, w*||mem_i||) per row, then gather from normalized bf16 rows.

#define TPB 256

typedef __bf16 bf16x8 __attribute__((ext_vector_type(8)));
typedef float  f32x4  __attribute__((ext_vector_type(4)));

typedef const __attribute__((address_space(1))) void* gas_ptr;
typedef __attribute__((address_space(3))) void*       las_ptr;

__device__ __forceinline__ unsigned short f2bf(float f) {
    __hip_bfloat16 h = __float2bfloat16(f);
    union { __hip_bfloat16 h; unsigned short s; } u; u.h = h; return u.s;
}

__device__ __forceinline__ float bf2f(unsigned short s) {
    union { unsigned int b; float f; } u; u.b = (unsigned int)s << 16; return u.f;
}

__device__ __forceinline__ float block_reduce_sum(float v, float* sred) {
    #pragma unroll
    for (int off = 32; off > 0; off >>= 1) v += __shfl_down(v, off, 64);
    int lane = threadIdx.x & 63;
    int wid  = threadIdx.x >> 6;
    if (lane == 0) sred[wid] = v;
    __syncthreads();
    if (threadIdx.x == 0) {
        float s = 0.f;
        for (int i = 0; i < 4; ++i) s += sred[i];
        sred[0] = s;
    }
    __syncthreads();
    float r = sred[0];
    __syncthreads();
    return r;
}

// One block per row: y_bf16 = x / sqrt(sum(x^2) + 1e-6); optionally store the norm.
__global__ __launch_bounds__(TPB) void normalize_rows_bf16(const float* __restrict__ X,
                                                           unsigned short* __restrict__ Y,
                                                           float* __restrict__ norms,
                                                           int cols) {
    __shared__ float sred[4];
    int row = blockIdx.x, tid = threadIdx.x;
    const float4* x4 = (const float4*)(X + (size_t)row * cols);
    ushort4* y4 = (ushort4*)(Y + (size_t)row * cols);
    int n4 = cols >> 2;
    float ss = 0.f;
    for (int i = tid; i < n4; i += TPB) {
        float4 v = x4[i];
        ss += v.x * v.x + v.y * v.y + v.z * v.z + v.w * v.w;
    }
    float tot = block_reduce_sum(ss, sred);
    float nrm = sqrtf(tot + 1e-6f);
    float inv = 1.0f / nrm;
    if (norms && tid == 0) norms[row] = nrm;
    for (int i = tid; i < n4; i += TPB) {
        float4 v = x4[i];
        ushort4 o;
        o.x = f2bf(v.x * inv); o.y = f2bf(v.y * inv);
        o.z = f2bf(v.z * inv); o.w = f2bf(v.w * inv);
        y4[i] = o;
    }
}

// Transpose + cast: in fp32 [R][C] -> out bf16 [Cpad][R]; rows c in [C, Cpad) are zero.
__global__ __launch_bounds__(TPB) void transpose_cast(const float* __restrict__ in,
                                                      unsigned short* __restrict__ out,
                                                      int R, int C, int Cpad) {
    __shared__ float t[32][33];
    int x = threadIdx.x & 31, y = threadIdx.x >> 5;
    int r0 = blockIdx.y * 32, c0 = blockIdx.x * 32;
    #pragma unroll
    for (int yy = y; yy < 32; yy += 8) {
        int c = c0 + x;
        t[yy][x] = (c < C) ? in[(size_t)(r0 + yy) * C + c] : 0.f;
    }
    __syncthreads();
    #pragma unroll
    for (int yy = y; yy < 32; yy += 8) {
        int c = c0 + yy;
        if (c < Cpad)
            out[(size_t)c * R + r0 + x] = f2bf(t[x][yy]);
    }
}

// Sparsemax (Michelot fixed point, exact) over rows of Z [rows][m], m <= 8192.
// Compacts in place over the fp32 row: packed[j] = (idx << 16) | bf16(w * ynorm[idx]),
// count -> cnt[row]. idx < 8192 fits in 13 bits; order within a row is arbitrary.
__global__ __launch_bounds__(TPB) void sparsemax_compact(float* __restrict__ Z,
                                                         const float* __restrict__ ynorm,
                                                         int* __restrict__ cnt, int m) {
    __shared__ float sz[8192];
    __shared__ float sred[4];
    __shared__ unsigned int lcnt;
    int row = blockIdx.x, tid = threadIdx.x;
    float* zrow = Z + (size_t)row * m;
    int n4 = m >> 2;
    float4* sz4 = (float4*)sz;
    const float4* zr4 = (const float4*)zrow;
    for (int i = tid; i < n4; i += TPB) sz4[i] = zr4[i];
    if (tid == 0) lcnt = 0;
    __syncthreads();

    float ps = 0.f;
    for (int i = tid; i < m; i += TPB) ps += sz[i];
    float tot = block_reduce_sum(ps, sred);
    float tau = (tot - 1.0f) / (float)m;
    float prev_cnt = (float)m;

    for (int it = 0; it < 64; ++it) {
        float s = 0.f, c = 0.f;
        for (int i = tid; i < m; i += TPB) {
            float z = sz[i];
            if (z > tau) { s += z; c += 1.0f; }
        }
        s = block_reduce_sum(s, sred);
        c = block_reduce_sum(c, sred);
        if (c < 0.5f) break;
        if (c == prev_cnt) break;
        tau = (s - 1.0f) / c;
        prev_cnt = c;
    }

    unsigned int* prow = (unsigned int*)zrow;   // overlay: reads all done above
    for (int i = tid; i < m; i += TPB) {
        float w = sz[i] - tau;
        if (w > 0.f) {
            float wn = w * ynorm[i];
            unsigned int slot = atomicAdd(&lcnt, 1u);
            prow[slot] = ((unsigned int)i << 16) | (unsigned int)f2bf(wn);
        }
    }
    __syncthreads();
    if (tid == 0) cnt[row] = (int)lcnt;
}

// mv[row] = sum_j w_j * yhat[idx_j]  (== sum_j sparsemax_w * mem[idx_j]).
// One block per row; thread t owns cols 4t..4t+3 (d == 1024 == 4*TPB).
__global__ __launch_bounds__(TPB) void sparse_mv(const unsigned int* __restrict__ packed,
                                                 const int* __restrict__ cnt,
                                                 const unsigned short* __restrict__ yn,
                                                 unsigned short* __restrict__ mv,
                                                 int m, int d) {
    __shared__ unsigned int sl[TPB];
    int row = blockIdx.x, tid = threadIdx.x;
    const unsigned int* prow = packed + (size_t)row * m;
    int n = cnt[row];
    int c0 = tid * 4;
    float acc0 = 0.f, acc1 = 0.f, acc2 = 0.f, acc3 = 0.f;
    for (int j0 = 0; j0 < n; j0 += TPB) {
        int chunk = min(TPB, n - j0);
        __syncthreads();
        if (tid < chunk) sl[tid] = prow[j0 + tid];
        __syncthreads();
        #pragma unroll 4
        for (int jj = 0; jj < chunk; ++jj) {
            unsigned int u = sl[jj];
            int idx = (int)(u >> 16);
            float w = bf2f((unsigned short)(u & 0xffffu));
            ushort4 v = *(const ushort4*)&yn[(size_t)idx * d + c0];
            acc0 += w * bf2f(v.x);
            acc1 += w * bf2f(v.y);
            acc2 += w * bf2f(v.z);
            acc3 += w * bf2f(v.w);
        }
    }
    ushort4 o;
    o.x = f2bf(acc0); o.y = f2bf(acc1); o.z = f2bf(acc2); o.w = f2bf(acc3);
    *(ushort4*)&mv[(size_t)row * d + c0] = o;
}

// C[M][ldc] = A[M][lda(bf16)] * B^T  (+bias)(+relu).  B is [Npad][K] bf16 row-major.
// 128x128 tile, BK=32, 256 threads = 4 waves (2x2), mfma_f32_16x16x32_bf16.
template <int STORE_BF16, int RELU, int HASBIAS>
__global__ __launch_bounds__(TPB) void gemm_bt(const unsigned short* __restrict__ A,
                                               const unsigned short* __restrict__ B,
                                               const float* __restrict__ bias,
                                               void* __restrict__ C,
                                               int M, int K, int lda, int NOUT, int ldc) {
    __shared__ unsigned short lA[128 * 32];
    __shared__ unsigned short lB[128 * 32];
    int tid = threadIdx.x;
    int lane = tid & 63, wv = tid >> 6;
    int wm = (wv & 1) * 64, wn = (wv >> 1) * 64;
    int lr = lane & 15, kq = lane >> 4;

    int rowBase = blockIdx.y * 128;
    int colBase = blockIdx.x * 128;

    f32x4 acc[4][4] = {};

    for (int k0 = 0; k0 < K; k0 += 32) {
        #pragma unroll
        for (int l = 0; l < 2; ++l) {
            int li = l * 256 + tid;
            int row = li >> 2, seg = li & 3;
            const char* g = (const char*)(A + (size_t)(rowBase + row) * lda + k0) + seg * 16;
            __builtin_amdgcn_global_load_lds((gas_ptr)g, (las_ptr)((char*)lA + li * 16), 16, 0, 0);
        }
        #pragma unroll
        for (int l = 0; l < 2; ++l) {
            int li = l * 256 + tid;
            int row = li >> 2, seg = li & 3;
            const char* g = (const char*)(B + (size_t)(colBase + row) * K + k0) + seg * 16;
            __builtin_amdgcn_global_load_lds((gas_ptr)g, (las_ptr)((char*)lB + li * 16), 16, 0, 0);
        }
        __syncthreads();

        bf16x8 av[4], bv[4];
        #pragma unroll
        for (int i = 0; i < 4; ++i)
            av[i] = *(const bf16x8*)&lA[(wm + i * 16 + lr) * 32 + kq * 8];
        #pragma unroll
        for (int j = 0; j < 4; ++j)
            bv[j] = *(const bf16x8*)&lB[(wn + j * 16 + lr) * 32 + kq * 8];
        #pragma unroll
        for (int i = 0; i < 4; ++i)
            #pragma unroll
            for (int j = 0; j < 4; ++j)
                acc[i][j] = __builtin_amdgcn_mfma_f32_16x16x32_bf16(av[i], bv[j], acc[i][j], 0, 0, 0);
        __syncthreads();
    }

    float* Cf = (float*)C;
    unsigned short* Cb = (unsigned short*)C;
    #pragma unroll
    for (int j = 0; j < 4; ++j) {
        int col = colBase + wn + j * 16 + lr;
        if (col >= NOUT) continue;
        float bv_ = HASBIAS ? bias[col] : 0.f;
        #pragma unroll
        for (int i = 0; i < 4; ++i) {
            #pragma unroll
            for (int r = 0; r < 4; ++r) {
                int row = rowBase + wm + i * 16 + kq * 4 + r;
                float v = acc[i][j][r] + bv_;
                if (RELU) v = fmaxf(v, 0.f);
                if (STORE_BF16) Cb[(size_t)row * ldc + col] = f2bf(v);
                else            Cf[(size_t)row * ldc + col] = v;
            }
        }
    }
}

extern "C" void kernel_launch(void* const* d_in, const int* in_sizes, int n_in,
                              void* d_out, int out_size, void* d_ws, size_t ws_size,
                              hipStream_t stream) {
    const float* enc = (const float*)d_in[0];   // [b, d]
    const float* mem = (const float*)d_in[1];   // [m, d]
    const float* W1  = (const float*)d_in[2];   // [d, 2d]
    const float* b1  = (const float*)d_in[3];   // [2d]
    const float* W2  = (const float*)d_in[4];   // [2d, out]
    const float* b2  = (const float*)d_in[5];   // [out]

    const int d    = in_sizes[3] / 2;           // 1024
    const int b    = in_sizes[0] / d;           // 2048
    const int m    = in_sizes[1] / d;           // 8192
    const int d2   = in_sizes[3];               // 2048
    const int outN = in_sizes[5];               // 1000
    const int outPad = 1024;

    unsigned short* xn    = (unsigned short*)d_ws;                    // [b][d] bf16
    unsigned short* yn    = xn  + (size_t)b * d;                      // [m][d] bf16
    float*          ynorm = (float*)(yn + (size_t)m * d);             // [m] fp32
    unsigned short* W1T   = (unsigned short*)(ynorm + m);             // [2d][d] bf16
    unsigned short* W2T   = W1T + (size_t)d2 * d;                     // [outPad][2d] bf16
    float*          Z     = (float*)(W2T + (size_t)outPad * d2);      // [b][m] fp32 / packed overlay
    int*            cnt   = (int*)(Z + (size_t)b * m);                // [b] int
    unsigned short* mv    = (unsigned short*)(cnt + b);               // [b][d] bf16
    unsigned short* h     = mv + (size_t)b * d;                       // [b][2d] bf16

    normalize_rows_bf16<<<b, TPB, 0, stream>>>(enc, xn, nullptr, d);
    normalize_rows_bf16<<<m, TPB, 0, stream>>>(mem, yn, ynorm, d);

    // W1 [d][2d] -> W1T [2d][d]
    transpose_cast<<<dim3(d2 / 32, d / 32), TPB, 0, stream>>>(W1, W1T, d, d2, d2);
    // W2 [2d][outN] -> W2T [outPad][2d], zero-padded
    transpose_cast<<<dim3(outPad / 32, d2 / 32), TPB, 0, stream>>>(W2, W2T, d2, outN, outPad);

    // Z = xn * yn^T   [b][m] fp32  (cosine similarity; sparsemax is shift-invariant)
    gemm_bt<0, 0, 0><<<dim3(m / 128, b / 128), TPB, 0, stream>>>(xn, yn, nullptr, Z,
                                                                 b, d, d, m, m);
    // sparsemax + in-place compaction to (idx, w*||mem_i||) pairs
    sparsemax_compact<<<b, TPB, 0, stream>>>(Z, ynorm, cnt, m);

    // mv = sum_support w_i * mem_i  via gather from normalized bf16 rows
    sparse_mv<<<b, TPB, 0, stream>>>((const unsigned int*)Z, cnt, yn, mv, m, d);

    // h = relu(mv * W1 + b1)   [b][2d] bf16
    gemm_bt<1, 1, 1><<<dim3(d2 / 128, b / 128), TPB, 0, stream>>>(mv, W1T, b1, h,
                                                                  b, d, d, d2, d2);
    // out = h * W2 + b2   [b][outN] fp32
    gemm_bt<0, 0, 1><<<dim3(outPad / 128, b / 128), TPB, 0, stream>>>(h, W2T, b2, d_out,
                                                                      b, d2, d2, outN, outN);
}

// Round 4
// 302.293 us; speedup vs baseline: 10.0845x; 1.1154x over previous
//
#include <hip/hip_runtime.h>
#include <hip/hip_bf16.h>

// b=2048, m=8192, d=1024, 2d=2048, out=1000. fp32 in/out, bf16 MFMA GEMMs.
// mv = sparsemax(Z) @ mem exploits sparsemax support sparsity (~100/8192).
// Sparsemax: moment-guess threshold + compaction => 3 full-row passes instead of ~15.

#define TPB 256
#define CAP 1024   // compact-list capacity; fallback to full-row Michelot if exceeded

typedef __bf16 bf16x8 __attribute__((ext_vector_type(8)));
typedef float  f32x4  __attribute__((ext_vector_type(4)));

typedef const __attribute__((address_space(1))) void* gas_ptr;
typedef __attribute__((address_space(3))) void*       las_ptr;

__device__ __forceinline__ unsigned short f2bf(float f) {
    __hip_bfloat16 h = __float2bfloat16(f);
    union { __hip_bfloat16 h; unsigned short s; } u; u.h = h; return u.s;
}

__device__ __forceinline__ float bf2f(unsigned short s) {
    union { unsigned int b; float f; } u; u.b = (unsigned int)s << 16; return u.f;
}

__device__ __forceinline__ float block_reduce_sum(float v, float* sred) {
    #pragma unroll
    for (int off = 32; off > 0; off >>= 1) v += __shfl_down(v, off, 64);
    int lane = threadIdx.x & 63;
    int wid  = threadIdx.x >> 6;
    if (lane == 0) sred[wid] = v;
    __syncthreads();
    if (threadIdx.x == 0) {
        float s = 0.f;
        for (int i = 0; i < 4; ++i) s += sred[i];
        sred[0] = s;
    }
    __syncthreads();
    float r = sred[0];
    __syncthreads();
    return r;
}

// Reduce two values with one LDS round-trip.
__device__ __forceinline__ void block_reduce_sum2(float& a, float& b, float* sred) {
    #pragma unroll
    for (int off = 32; off > 0; off >>= 1) {
        a += __shfl_down(a, off, 64);
        b += __shfl_down(b, off, 64);
    }
    int lane = threadIdx.x & 63, wid = threadIdx.x >> 6;
    if (lane == 0) { sred[wid] = a; sred[4 + wid] = b; }
    __syncthreads();
    if (threadIdx.x == 0) {
        sred[0] = sred[0] + sred[1] + sred[2] + sred[3];
        sred[4] = sred[4] + sred[5] + sred[6] + sred[7];
    }
    __syncthreads();
    a = sred[0]; b = sred[4];
    __syncthreads();
}

// One block per row: y_bf16 = x / sqrt(sum(x^2) + 1e-6); optionally store the norm.
__global__ __launch_bounds__(TPB) void normalize_rows_bf16(const float* __restrict__ X,
                                                           unsigned short* __restrict__ Y,
                                                           float* __restrict__ norms,
                                                           int cols) {
    __shared__ float sred[4];
    int row = blockIdx.x, tid = threadIdx.x;
    const float4* x4 = (const float4*)(X + (size_t)row * cols);
    ushort4* y4 = (ushort4*)(Y + (size_t)row * cols);
    int n4 = cols >> 2;
    float ss = 0.f;
    for (int i = tid; i < n4; i += TPB) {
        float4 v = x4[i];
        ss += v.x * v.x + v.y * v.y + v.z * v.z + v.w * v.w;
    }
    float tot = block_reduce_sum(ss, sred);
    float nrm = sqrtf(tot + 1e-6f);
    float inv = 1.0f / nrm;
    if (norms && tid == 0) norms[row] = nrm;
    for (int i = tid; i < n4; i += TPB) {
        float4 v = x4[i];
        ushort4 o;
        o.x = f2bf(v.x * inv); o.y = f2bf(v.y * inv);
        o.z = f2bf(v.z * inv); o.w = f2bf(v.w * inv);
        y4[i] = o;
    }
}

// Transpose + cast: in fp32 [R][C] -> out bf16 [Cpad][R]; rows c in [C, Cpad) are zero.
__global__ __launch_bounds__(TPB) void transpose_cast(const float* __restrict__ in,
                                                      unsigned short* __restrict__ out,
                                                      int R, int C, int Cpad) {
    __shared__ float t[32][33];
    int x = threadIdx.x & 31, y = threadIdx.x >> 5;
    int r0 = blockIdx.y * 32, c0 = blockIdx.x * 32;
    #pragma unroll
    for (int yy = y; yy < 32; yy += 8) {
        int c = c0 + x;
        t[yy][x] = (c < C) ? in[(size_t)(r0 + yy) * C + c] : 0.f;
    }
    __syncthreads();
    #pragma unroll
    for (int yy = y; yy < 32; yy += 8) {
        int c = c0 + yy;
        if (c < Cpad)
            out[(size_t)c * R + r0 + x] = f2bf(t[x][yy]);
    }
}

// Sparsemax over rows of Z [rows][m] (exact; Michelot fixed point with a
// moment-based head start + active-set compaction). Compacts in place:
// packed[j] = (idx << 16) | bf16(w * ynorm[idx]); count -> cnt[row].
__global__ __launch_bounds__(TPB) void sparsemax_compact(float* __restrict__ Z,
                                                         const float* __restrict__ ynorm,
                                                         int* __restrict__ cnt, int m) {
    __shared__ float sz[8192];
    __shared__ float sred[8];
    __shared__ unsigned short cidx[CAP];
    __shared__ float cval[CAP];
    __shared__ unsigned int lcnt, ocnt;
    int row = blockIdx.x, tid = threadIdx.x;
    float* zrow = Z + (size_t)row * m;
    unsigned int* prow = (unsigned int*)zrow;   // packed overlay (written after all reads)
    int n4 = m >> 2;
    float4* sz4 = (float4*)sz;
    const float4* zr4 = (const float4*)zrow;

    // Pass A: load + sum + sumsq
    float s = 0.f, q = 0.f;
    for (int i = tid; i < n4; i += TPB) {
        float4 v = zr4[i];
        sz4[i] = v;
        s += v.x + v.y + v.z + v.w;
        q += v.x * v.x + v.y * v.y + v.z * v.z + v.w * v.w;
    }
    if (tid == 0) { lcnt = 0; ocnt = 0; }
    block_reduce_sum2(s, q, sred);
    float fm   = (float)m;
    float mean = s / fm;
    float sig  = sqrtf(fmaxf(q / fm - mean * mean, 0.f));
    float tau_s = (s - 1.f) / fm;          // first Michelot iterate: always <= tau*
    float tau_g = mean + 2.f * sig;        // aggressive guess; valid iff S(tau_g) >= 1

    // Pass B: excess-sum and count at both thresholds
    float Sg = 0.f, cg = 0.f, Ss = 0.f, cs = 0.f;
    for (int i = tid; i < m; i += TPB) {
        float z = sz[i];
        if (z > tau_g) { Sg += z - tau_g; cg += 1.f; }
        if (z > tau_s) { Ss += z - tau_s; cs += 1.f; }
    }
    block_reduce_sum2(Sg, cg, sred);
    block_reduce_sum2(Ss, cs, sred);

    float tau_lb, S_act, c_act;
    if (Sg >= 1.f) { tau_lb = tau_g; S_act = Sg + cg * tau_g; c_act = cg; }
    else           { tau_lb = tau_s; S_act = Ss + cs * tau_s; c_act = cs; }
    float tau1 = (S_act - 1.f) / c_act;    // one Michelot step from a support superset
    if (tau1 < tau_lb) tau1 = tau_lb;      // numeric guard

    // Pass C: compact actives at tau1
    for (int i = tid; i < m; i += TPB) {
        float z = sz[i];
        if (z > tau1) {
            unsigned int slot = atomicAdd(&lcnt, 1u);
            if (slot < CAP) { cidx[slot] = (unsigned short)i; cval[slot] = z; }
        }
    }
    __syncthreads();

    if (lcnt <= CAP && lcnt > 0) {
        // Fast path: Michelot on the compact list
        int n = (int)lcnt;
        float tau = tau1, prev = -1.f;
        for (int it = 0; it < 64; ++it) {
            float S = 0.f, c = 0.f;
            for (int j = tid; j < n; j += TPB) {
                float z = cval[j];
                if (z > tau) { S += z; c += 1.f; }
            }
            block_reduce_sum2(S, c, sred);
            if (c < 0.5f || c == prev) break;
            tau = (S - 1.f) / c; prev = c;
        }
        for (int j = tid; j < n; j += TPB) {
            float w = cval[j] - tau;
            if (w > 0.f) {
                int idx = (int)cidx[j];
                unsigned int slot = atomicAdd(&ocnt, 1u);
                prow[slot] = ((unsigned int)idx << 16) | (unsigned int)f2bf(w * ynorm[idx]);
            }
        }
        __syncthreads();
        if (tid == 0) cnt[row] = (int)ocnt;
    } else {
        // Fallback: classic full-row Michelot from tau1 (correct for any input)
        float tau = tau1, prev = -1.f;
        for (int it = 0; it < 64; ++it) {
            float S = 0.f, c = 0.f;
            for (int i = tid; i < m; i += TPB) {
                float z = sz[i];
                if (z > tau) { S += z; c += 1.f; }
            }
            block_reduce_sum2(S, c, sred);
            if (c < 0.5f || c == prev) break;
            tau = (S - 1.f) / c; prev = c;
        }
        for (int i = tid; i < m; i += TPB) {
            float w = sz[i] - tau;
            if (w > 0.f) {
                unsigned int slot = atomicAdd(&ocnt, 1u);
                prow[slot] = ((unsigned int)i << 16) | (unsigned int)f2bf(w * ynorm[i]);
            }
        }
        __syncthreads();
        if (tid == 0) cnt[row] = (int)ocnt;
    }
}

// mv[row] = sum_j w_j * yhat[idx_j]  (== sum_j sparsemax_w * mem[idx_j]).
__global__ __launch_bounds__(TPB) void sparse_mv(const unsigned int* __restrict__ packed,
                                                 const int* __restrict__ cnt,
                                                 const unsigned short* __restrict__ yn,
                                                 unsigned short* __restrict__ mv,
                                                 int m, int d) {
    __shared__ unsigned int sl[TPB];
    int row = blockIdx.x, tid = threadIdx.x;
    const unsigned int* prow = packed + (size_t)row * m;
    int n = cnt[row];
    int c0 = tid * 4;
    float acc0 = 0.f, acc1 = 0.f, acc2 = 0.f, acc3 = 0.f;
    for (int j0 = 0; j0 < n; j0 += TPB) {
        int chunk = min(TPB, n - j0);
        __syncthreads();
        if (tid < chunk) sl[tid] = prow[j0 + tid];
        __syncthreads();
        #pragma unroll 4
        for (int jj = 0; jj < chunk; ++jj) {
            unsigned int u = sl[jj];
            int idx = (int)(u >> 16);
            float w = bf2f((unsigned short)(u & 0xffffu));
            ushort4 v = *(const ushort4*)&yn[(size_t)idx * d + c0];
            acc0 += w * bf2f(v.x);
            acc1 += w * bf2f(v.y);
            acc2 += w * bf2f(v.z);
            acc3 += w * bf2f(v.w);
        }
    }
    ushort4 o;
    o.x = f2bf(acc0); o.y = f2bf(acc1); o.z = f2bf(acc2); o.w = f2bf(acc3);
    *(ushort4*)&mv[(size_t)row * d + c0] = o;
}

// C[M][ldc] = A[M][lda(bf16)] * B^T  (+bias)(+relu).  B is [Npad][K] bf16 row-major.
// 128xBN tile (BN = 128 or 64), BK=32, 256 threads = 4 waves, mfma_f32_16x16x32_bf16.
// BN=128: waves 2x2, 4x4 MFMA tiles each. BN=64: waves stacked 4x1, 2x4 tiles each.
template <int BN, int STORE_BF16, int RELU, int HASBIAS>
__global__ __launch_bounds__(TPB) void gemm_bt(const unsigned short* __restrict__ A,
                                               const unsigned short* __restrict__ B,
                                               const float* __restrict__ bias,
                                               void* __restrict__ C,
                                               int M, int K, int lda, int NOUT, int ldc) {
    constexpr int IT = (BN == 128) ? 4 : 2;
    __shared__ unsigned short lA[128 * 32];
    __shared__ unsigned short lB[BN * 32];
    int tid = threadIdx.x;
    int lane = tid & 63, wv = tid >> 6;
    int wm = (BN == 128) ? (wv & 1) * 64 : wv * 32;
    int wn = (BN == 128) ? (wv >> 1) * 64 : 0;
    int lr = lane & 15, kq = lane >> 4;

    int rowBase = blockIdx.y * 128;
    int colBase = blockIdx.x * BN;

    f32x4 acc[IT][4] = {};

    for (int k0 = 0; k0 < K; k0 += 32) {
        #pragma unroll
        for (int l = 0; l < 2; ++l) {
            int li = l * 256 + tid;
            int r = li >> 2, seg = li & 3;
            const char* g = (const char*)(A + (size_t)(rowBase + r) * lda + k0) + seg * 16;
            __builtin_amdgcn_global_load_lds((gas_ptr)g, (las_ptr)((char*)lA + li * 16), 16, 0, 0);
        }
        #pragma unroll
        for (int l = 0; l < BN / 64; ++l) {
            int li = l * 256 + tid;
            int r = li >> 2, seg = li & 3;
            const char* g = (const char*)(B + (size_t)(colBase + r) * K + k0) + seg * 16;
            __builtin_amdgcn_global_load_lds((gas_ptr)g, (las_ptr)((char*)lB + li * 16), 16, 0, 0);
        }
        __syncthreads();

        bf16x8 av[IT], bv[4];
        #pragma unroll
        for (int i = 0; i < IT; ++i)
            av[i] = *(const bf16x8*)&lA[(wm + i * 16 + lr) * 32 + kq * 8];
        #pragma unroll
        for (int j = 0; j < 4; ++j)
            bv[j] = *(const bf16x8*)&lB[(wn + j * 16 + lr) * 32 + kq * 8];
        #pragma unroll
        for (int i = 0; i < IT; ++i)
            #pragma unroll
            for (int j = 0; j < 4; ++j)
                acc[i][j] = __builtin_amdgcn_mfma_f32_16x16x32_bf16(av[i], bv[j], acc[i][j], 0, 0, 0);
        __syncthreads();
    }

    float* Cf = (float*)C;
    unsigned short* Cb = (unsigned short*)C;
    #pragma unroll
    for (int j = 0; j < 4; ++j) {
        int col = colBase + wn + j * 16 + lr;
        if (col >= NOUT) continue;
        float bv_ = HASBIAS ? bias[col] : 0.f;
        #pragma unroll
        for (int i = 0; i < IT; ++i) {
            #pragma unroll
            for (int r = 0; r < 4; ++r) {
                int row = rowBase + wm + i * 16 + kq * 4 + r;
                float v = acc[i][j][r] + bv_;
                if (RELU) v = fmaxf(v, 0.f);
                if (STORE_BF16) Cb[(size_t)row * ldc + col] = f2bf(v);
                else            Cf[(size_t)row * ldc + col] = v;
            }
        }
    }
}

extern "C" void kernel_launch(void* const* d_in, const int* in_sizes, int n_in,
                              void* d_out, int out_size, void* d_ws, size_t ws_size,
                              hipStream_t stream) {
    const float* enc = (const float*)d_in[0];   // [b, d]
    const float* mem = (const float*)d_in[1];   // [m, d]
    const float* W1  = (const float*)d_in[2];   // [d, 2d]
    const float* b1  = (const float*)d_in[3];   // [2d]
    const float* W2  = (const float*)d_in[4];   // [2d, out]
    const float* b2  = (const float*)d_in[5];   // [out]

    const int d    = in_sizes[3] / 2;           // 1024
    const int b    = in_sizes[0] / d;           // 2048
    const int m    = in_sizes[1] / d;           // 8192
    const int d2   = in_sizes[3];               // 2048
    const int outN = in_sizes[5];               // 1000
    const int outPad = 1024;

    unsigned short* xn    = (unsigned short*)d_ws;                    // [b][d] bf16
    unsigned short* yn    = xn  + (size_t)b * d;                      // [m][d] bf16
    float*          ynorm = (float*)(yn + (size_t)m * d);             // [m] fp32
    unsigned short* W1T   = (unsigned short*)(ynorm + m);             // [2d][d] bf16
    unsigned short* W2T   = W1T + (size_t)d2 * d;                     // [outPad][2d] bf16
    float*          Z     = (float*)(W2T + (size_t)outPad * d2);      // [b][m] fp32 / packed overlay
    int*            cnt   = (int*)(Z + (size_t)b * m);                // [b] int
    unsigned short* mv    = (unsigned short*)(cnt + b);               // [b][d] bf16
    unsigned short* h     = mv + (size_t)b * d;                       // [b][2d] bf16

    normalize_rows_bf16<<<b, TPB, 0, stream>>>(enc, xn, nullptr, d);
    normalize_rows_bf16<<<m, TPB, 0, stream>>>(mem, yn, ynorm, d);

    // W1 [d][2d] -> W1T [2d][d]
    transpose_cast<<<dim3(d2 / 32, d / 32), TPB, 0, stream>>>(W1, W1T, d, d2, d2);
    // W2 [2d][outN] -> W2T [outPad][2d], zero-padded
    transpose_cast<<<dim3(outPad / 32, d2 / 32), TPB, 0, stream>>>(W2, W2T, d2, outN, outPad);

    // Z = xn * yn^T   [b][m] fp32  (cosine similarity; sparsemax is shift-invariant)
    gemm_bt<128, 0, 0, 0><<<dim3(m / 128, b / 128), TPB, 0, stream>>>(xn, yn, nullptr, Z,
                                                                      b, d, d, m, m);
    // sparsemax + in-place compaction to (idx, w*||mem_i||) pairs
    sparsemax_compact<<<b, TPB, 0, stream>>>(Z, ynorm, cnt, m);

    // mv = sum_support w_i * mem_i  via gather from normalized bf16 rows
    sparse_mv<<<b, TPB, 0, stream>>>((const unsigned int*)Z, cnt, yn, mv, m, d);

    // h = relu(mv * W1 + b1)   [b][2d] bf16   (BN=64 -> 512 blocks)
    gemm_bt<64, 1, 1, 1><<<dim3(d2 / 64, b / 128), TPB, 0, stream>>>(mv, W1T, b1, h,
                                                                     b, d, d, d2, d2);
    // out = h * W2 + b2   [b][outN] fp32      (BN=64 -> 256 blocks)
    gemm_bt<64, 0, 0, 1><<<dim3(outPad / 64, b / 128), TPB, 0, stream>>>(h, W2T, b2, d_out,
                                                                         b, d2, d2, outN, outN);
}

// Round 5
// 275.852 us; speedup vs baseline: 11.0511x; 1.0959x over previous
//
#include <hip/hip_runtime.h>
#include <hip/hip_bf16.h>

// b=2048, m=8192, d=1024, 2d=2048, out=1000. fp32 in/out, bf16 MFMA GEMMs.
// Z (cosine scores) kept in fp16 (range [-1,1], eps ~5e-5: below bf16-dot noise).
// mv = sparsemax(Z) @ mem exploits sparsemax support sparsity (~100/8192).
// GEMM: 128xBN tile, BK=64, XOR-swizzled LDS staging (conflict-free ds_read_b128).

#define TPB 256
#define CAP 1024   // compact-list capacity; fallback to full-row Michelot if exceeded
#define BK 64

typedef __bf16 bf16x8 __attribute__((ext_vector_type(8)));
typedef float  f32x4  __attribute__((ext_vector_type(4)));

typedef const __attribute__((address_space(1))) void* gas_ptr;
typedef __attribute__((address_space(3))) void*       las_ptr;

__device__ __forceinline__ unsigned short f2bf(float f) {
    __hip_bfloat16 h = __float2bfloat16(f);
    union { __hip_bfloat16 h; unsigned short s; } u; u.h = h; return u.s;
}
__device__ __forceinline__ float bf2f(unsigned short s) {
    union { unsigned int b; float f; } u; u.b = (unsigned int)s << 16; return u.f;
}
__device__ __forceinline__ unsigned short f2h(float f) {
    union { _Float16 h; unsigned short s; } u; u.h = (_Float16)f; return u.s;
}
__device__ __forceinline__ float h2f(unsigned short s) {
    union { unsigned short s; _Float16 h; } u; u.s = s; return (float)u.h;
}

__device__ __forceinline__ float block_reduce_sum(float v, float* sred) {
    #pragma unroll
    for (int off = 32; off > 0; off >>= 1) v += __shfl_down(v, off, 64);
    int lane = threadIdx.x & 63, wid = threadIdx.x >> 6;
    if (lane == 0) sred[wid] = v;
    __syncthreads();
    if (threadIdx.x == 0) sred[0] = sred[0] + sred[1] + sred[2] + sred[3];
    __syncthreads();
    float r = sred[0];
    __syncthreads();
    return r;
}

// Reduce two values with one LDS round-trip.
__device__ __forceinline__ void block_reduce_sum2(float& a, float& b, float* sred) {
    #pragma unroll
    for (int off = 32; off > 0; off >>= 1) {
        a += __shfl_down(a, off, 64);
        b += __shfl_down(b, off, 64);
    }
    int lane = threadIdx.x & 63, wid = threadIdx.x >> 6;
    if (lane == 0) { sred[wid] = a; sred[4 + wid] = b; }
    __syncthreads();
    if (threadIdx.x == 0) {
        sred[0] = sred[0] + sred[1] + sred[2] + sred[3];
        sred[4] = sred[4] + sred[5] + sred[6] + sred[7];
    }
    __syncthreads();
    a = sred[0]; b = sred[4];
    __syncthreads();
}

// Merged: rows [0,nrow0) normalize X0->Y0; rows [nrow0, nrow0+nrow1) normalize
// X1->Y1 and record the norm. y = x / sqrt(sum x^2 + 1e-6), bf16 out.
__global__ __launch_bounds__(TPB) void normalize_rows_bf16(const float* __restrict__ X0,
                                                           unsigned short* __restrict__ Y0,
                                                           const float* __restrict__ X1,
                                                           unsigned short* __restrict__ Y1,
                                                           float* __restrict__ norms1,
                                                           int nrow0, int cols) {
    __shared__ float sred[4];
    int r = blockIdx.x, tid = threadIdx.x;
    const float* X; unsigned short* Y; float* nn; int row;
    if (r < nrow0) { X = X0; Y = Y0; nn = nullptr; row = r; }
    else           { X = X1; Y = Y1; nn = norms1; row = r - nrow0; }
    const float4* x4 = (const float4*)(X + (size_t)row * cols);
    ushort4* y4 = (ushort4*)(Y + (size_t)row * cols);
    int n4 = cols >> 2;
    float ss = 0.f;
    for (int i = tid; i < n4; i += TPB) {
        float4 v = x4[i];
        ss += v.x * v.x + v.y * v.y + v.z * v.z + v.w * v.w;
    }
    float tot = block_reduce_sum(ss, sred);
    float nrm = sqrtf(tot + 1e-6f);
    float inv = 1.0f / nrm;
    if (nn && tid == 0) nn[row] = nrm;
    for (int i = tid; i < n4; i += TPB) {
        float4 v = x4[i];
        ushort4 o;
        o.x = f2bf(v.x * inv); o.y = f2bf(v.y * inv);
        o.z = f2bf(v.z * inv); o.w = f2bf(v.w * inv);
        y4[i] = o;
    }
}

// Transpose + cast: in fp32 [R][C] -> out bf16 [Cpad][R]; rows c in [C, Cpad) are zero.
__global__ __launch_bounds__(TPB) void transpose_cast(const float* __restrict__ in,
                                                      unsigned short* __restrict__ out,
                                                      int R, int C, int Cpad) {
    __shared__ float t[32][33];
    int x = threadIdx.x & 31, y = threadIdx.x >> 5;
    int r0 = blockIdx.y * 32, c0 = blockIdx.x * 32;
    #pragma unroll
    for (int yy = y; yy < 32; yy += 8) {
        int c = c0 + x;
        t[yy][x] = (c < C) ? in[(size_t)(r0 + yy) * C + c] : 0.f;
    }
    __syncthreads();
    #pragma unroll
    for (int yy = y; yy < 32; yy += 8) {
        int c = c0 + yy;
        if (c < Cpad)
            out[(size_t)c * R + r0 + x] = f2bf(t[x][yy]);
    }
}

// Sparsemax over fp16 rows of Z [rows][m] (exact; Michelot fixed point with a
// moment-based head start + active-set compaction). Compacts in place:
// packed[j] = (idx << 16) | bf16(w * ynorm[idx]); count -> cnt[row].
__global__ __launch_bounds__(TPB) void sparsemax_compact(unsigned short* __restrict__ Zh,
                                                         const float* __restrict__ ynorm,
                                                         int* __restrict__ cnt, int m) {
    __shared__ float sz[8192];
    __shared__ float sred[8];
    __shared__ unsigned short cidx[CAP];
    __shared__ float cval[CAP];
    __shared__ unsigned int lcnt, ocnt;
    int row = blockIdx.x, tid = threadIdx.x;
    unsigned short* zrow = Zh + (size_t)row * m;
    unsigned int* prow = (unsigned int*)zrow;   // packed overlay (written after all reads)
    const uint4* zr8 = (const uint4*)zrow;      // 8 halves per 16B
    int n8 = m >> 3;

    // Pass A: load fp16 -> fp32 LDS, + sum + sumsq
    float s = 0.f, q = 0.f;
    float4* sz4 = (float4*)sz;
    for (int i = tid; i < n8; i += TPB) {
        uint4 v = zr8[i];
        float4 a, bq;
        a.x = h2f((unsigned short)(v.x & 0xffffu)); a.y = h2f((unsigned short)(v.x >> 16));
        a.z = h2f((unsigned short)(v.y & 0xffffu)); a.w = h2f((unsigned short)(v.y >> 16));
        bq.x = h2f((unsigned short)(v.z & 0xffffu)); bq.y = h2f((unsigned short)(v.z >> 16));
        bq.z = h2f((unsigned short)(v.w & 0xffffu)); bq.w = h2f((unsigned short)(v.w >> 16));
        sz4[2 * i] = a; sz4[2 * i + 1] = bq;
        s += a.x + a.y + a.z + a.w + bq.x + bq.y + bq.z + bq.w;
        q += a.x * a.x + a.y * a.y + a.z * a.z + a.w * a.w
           + bq.x * bq.x + bq.y * bq.y + bq.z * bq.z + bq.w * bq.w;
    }
    if (tid == 0) { lcnt = 0; ocnt = 0; }
    block_reduce_sum2(s, q, sred);
    float fm   = (float)m;
    float mean = s / fm;
    float sig  = sqrtf(fmaxf(q / fm - mean * mean, 0.f));
    float tau_s = (s - 1.f) / fm;          // first Michelot iterate: always <= tau*
    float tau_g = mean + 2.f * sig;        // aggressive guess; valid iff S(tau_g) >= 1

    // Pass B: excess-sum and count at both thresholds
    float Sg = 0.f, cg = 0.f, Ss = 0.f, cs = 0.f;
    for (int i = tid; i < m; i += TPB) {
        float z = sz[i];
        if (z > tau_g) { Sg += z - tau_g; cg += 1.f; }
        if (z > tau_s) { Ss += z - tau_s; cs += 1.f; }
    }
    block_reduce_sum2(Sg, cg, sred);
    block_reduce_sum2(Ss, cs, sred);

    float tau_lb, S_act, c_act;
    if (Sg >= 1.f) { tau_lb = tau_g; S_act = Sg + cg * tau_g; c_act = cg; }
    else           { tau_lb = tau_s; S_act = Ss + cs * tau_s; c_act = cs; }
    float tau1 = (S_act - 1.f) / c_act;    // one Michelot step from a support superset
    if (tau1 < tau_lb) tau1 = tau_lb;      // numeric guard

    // Pass C: compact actives at tau1
    for (int i = tid; i < m; i += TPB) {
        float z = sz[i];
        if (z > tau1) {
            unsigned int slot = atomicAdd(&lcnt, 1u);
            if (slot < CAP) { cidx[slot] = (unsigned short)i; cval[slot] = z; }
        }
    }
    __syncthreads();

    if (lcnt <= CAP && lcnt > 0) {
        int n = (int)lcnt;
        float tau = tau1, prev = -1.f;
        for (int it = 0; it < 64; ++it) {
            float S = 0.f, c = 0.f;
            for (int j = tid; j < n; j += TPB) {
                float z = cval[j];
                if (z > tau) { S += z; c += 1.f; }
            }
            block_reduce_sum2(S, c, sred);
            if (c < 0.5f || c == prev) break;
            tau = (S - 1.f) / c; prev = c;
        }
        for (int j = tid; j < n; j += TPB) {
            float w = cval[j] - tau;
            if (w > 0.f) {
                int idx = (int)cidx[j];
                unsigned int slot = atomicAdd(&ocnt, 1u);
                prow[slot] = ((unsigned int)idx << 16) | (unsigned int)f2bf(w * ynorm[idx]);
            }
        }
        __syncthreads();
        if (tid == 0) cnt[row] = (int)ocnt;
    } else {
        // Fallback: classic full-row Michelot from tau1 (correct for any input)
        float tau = tau1, prev = -1.f;
        for (int it = 0; it < 64; ++it) {
            float S = 0.f, c = 0.f;
            for (int i = tid; i < m; i += TPB) {
                float z = sz[i];
                if (z > tau) { S += z; c += 1.f; }
            }
            block_reduce_sum2(S, c, sred);
            if (c < 0.5f || c == prev) break;
            tau = (S - 1.f) / c; prev = c;
        }
        for (int i = tid; i < m; i += TPB) {
            float w = sz[i] - tau;
            if (w > 0.f) {
                unsigned int slot = atomicAdd(&ocnt, 1u);
                prow[slot] = ((unsigned int)i << 16) | (unsigned int)f2bf(w * ynorm[i]);
            }
        }
        __syncthreads();
        if (tid == 0) cnt[row] = (int)ocnt;
    }
}

// mv[row] = sum_j w_j * yhat[idx_j]  (== sum_j sparsemax_w * mem[idx_j]).
__global__ __launch_bounds__(TPB) void sparse_mv(const unsigned int* __restrict__ packed,
                                                 const int* __restrict__ cnt,
                                                 const unsigned short* __restrict__ yn,
                                                 unsigned short* __restrict__ mv,
                                                 int pitchU, int d) {
    __shared__ unsigned int sl[TPB];
    int row = blockIdx.x, tid = threadIdx.x;
    const unsigned int* prow = packed + (size_t)row * pitchU;
    int n = cnt[row];
    int c0 = tid * 4;
    float acc0 = 0.f, acc1 = 0.f, acc2 = 0.f, acc3 = 0.f;
    for (int j0 = 0; j0 < n; j0 += TPB) {
        int chunk = min(TPB, n - j0);
        __syncthreads();
        if (tid < chunk) sl[tid] = prow[j0 + tid];
        __syncthreads();
        #pragma unroll 4
        for (int jj = 0; jj < chunk; ++jj) {
            unsigned int u = sl[jj];
            int idx = (int)(u >> 16);
            float w = bf2f((unsigned short)(u & 0xffffu));
            ushort4 v = *(const ushort4*)&yn[(size_t)idx * d + c0];
            acc0 += w * bf2f(v.x);
            acc1 += w * bf2f(v.y);
            acc2 += w * bf2f(v.z);
            acc3 += w * bf2f(v.w);
        }
    }
    ushort4 o;
    o.x = f2bf(acc0); o.y = f2bf(acc1); o.z = f2bf(acc2); o.w = f2bf(acc3);
    *(ushort4*)&mv[(size_t)row * d + c0] = o;
}

// C[M][ldc] = A[M][lda(bf16)] * B^T  (+bias)(+relu).  B is [Npad][K] bf16 row-major.
// 128xBN tile (BN 128 or 64), BK=64, 256 threads = 4 waves, mfma_f32_16x16x32_bf16.
// LDS staging XOR-swizzled: slot(row,seg) = row*8 + (seg ^ (row&7)), 16B segs ->
// fragment ds_read_b128 spreads over all banks (2-way max = free).
// OUTMODE: 0=f32, 1=bf16, 2=f16 store.
template <int BN, int OUTMODE, int RELU, int HASBIAS>
__global__ __launch_bounds__(TPB) void gemm_bt(const unsigned short* __restrict__ A,
                                               const unsigned short* __restrict__ B,
                                               const float* __restrict__ bias,
                                               void* __restrict__ C,
                                               int M, int K, int lda, int NOUT, int ldc) {
    constexpr int IT = (BN == 128) ? 4 : 2;
    __shared__ unsigned short lA[128 * BK];
    __shared__ unsigned short lB[BN * BK];
    int tid = threadIdx.x;
    int lane = tid & 63, wv = tid >> 6;
    int wm = (BN == 128) ? (wv & 1) * 64 : wv * 32;
    int wn = (BN == 128) ? (wv >> 1) * 64 : 0;
    int lr = lane & 15, kq = lane >> 4;

    int rowBase = blockIdx.y * 128;
    int colBase = blockIdx.x * BN;

    f32x4 acc[IT][4] = {};

    for (int k0 = 0; k0 < K; k0 += BK) {
        #pragma unroll
        for (int l = 0; l < 4; ++l) {
            int li = l * 256 + tid;
            int row = li >> 3, s0 = li & 7;
            int seg = s0 ^ (row & 7);
            const char* g = (const char*)(A + (size_t)(rowBase + row) * lda + k0) + seg * 16;
            __builtin_amdgcn_global_load_lds((gas_ptr)g, (las_ptr)((char*)lA + li * 16), 16, 0, 0);
        }
        #pragma unroll
        for (int l = 0; l < BN / 32; ++l) {
            int li = l * 256 + tid;
            int row = li >> 3, s0 = li & 7;
            int seg = s0 ^ (row & 7);
            const char* g = (const char*)(B + (size_t)(colBase + row) * K + k0) + seg * 16;
            __builtin_amdgcn_global_load_lds((gas_ptr)g, (las_ptr)((char*)lB + li * 16), 16, 0, 0);
        }
        __syncthreads();

        #pragma unroll
        for (int h = 0; h < 2; ++h) {
            bf16x8 av[IT], bv[4];
            #pragma unroll
            for (int i = 0; i < IT; ++i) {
                int row = wm + i * 16 + lr;
                av[i] = *(const bf16x8*)((const char*)lA + row * 128
                                         + ((((h << 2) | kq) ^ (row & 7)) * 16));
            }
            #pragma unroll
            for (int j = 0; j < 4; ++j) {
                int row = wn + j * 16 + lr;
                bv[j] = *(const bf16x8*)((const char*)lB + row * 128
                                         + ((((h << 2) | kq) ^ (row & 7)) * 16));
            }
            #pragma unroll
            for (int i = 0; i < IT; ++i)
                #pragma unroll
                for (int j = 0; j < 4; ++j)
                    acc[i][j] = __builtin_amdgcn_mfma_f32_16x16x32_bf16(av[i], bv[j], acc[i][j], 0, 0, 0);
        }
        __syncthreads();
    }

    float* Cf = (float*)C;
    unsigned short* Cb = (unsigned short*)C;
    #pragma unroll
    for (int j = 0; j < 4; ++j) {
        int col = colBase + wn + j * 16 + lr;
        if (col >= NOUT) continue;
        float bv_ = HASBIAS ? bias[col] : 0.f;
        #pragma unroll
        for (int i = 0; i < IT; ++i) {
            #pragma unroll
            for (int r = 0; r < 4; ++r) {
                int row = rowBase + wm + i * 16 + kq * 4 + r;
                float v = acc[i][j][r] + bv_;
                if (RELU) v = fmaxf(v, 0.f);
                if (OUTMODE == 0)      Cf[(size_t)row * ldc + col] = v;
                else if (OUTMODE == 1) Cb[(size_t)row * ldc + col] = f2bf(v);
                else                   Cb[(size_t)row * ldc + col] = f2h(v);
            }
        }
    }
}

extern "C" void kernel_launch(void* const* d_in, const int* in_sizes, int n_in,
                              void* d_out, int out_size, void* d_ws, size_t ws_size,
                              hipStream_t stream) {
    const float* enc = (const float*)d_in[0];   // [b, d]
    const float* mem = (const float*)d_in[1];   // [m, d]
    const float* W1  = (const float*)d_in[2];   // [d, 2d]
    const float* b1  = (const float*)d_in[3];   // [2d]
    const float* W2  = (const float*)d_in[4];   // [2d, out]
    const float* b2  = (const float*)d_in[5];   // [out]

    const int d    = in_sizes[3] / 2;           // 1024
    const int b    = in_sizes[0] / d;           // 2048
    const int m    = in_sizes[1] / d;           // 8192
    const int d2   = in_sizes[3];               // 2048
    const int outN = in_sizes[5];               // 1000
    const int outPad = 1024;

    unsigned short* xn    = (unsigned short*)d_ws;                    // [b][d] bf16
    unsigned short* yn    = xn  + (size_t)b * d;                      // [m][d] bf16
    float*          ynorm = (float*)(yn + (size_t)m * d);             // [m] fp32
    unsigned short* W1T   = (unsigned short*)(ynorm + m);             // [2d][d] bf16
    unsigned short* W2T   = W1T + (size_t)d2 * d;                     // [outPad][2d] bf16
    unsigned short* Zh    = W2T + (size_t)outPad * d2;                // [b][m] fp16 / packed overlay
    int*            cnt   = (int*)(Zh + (size_t)b * m);               // [b] int
    unsigned short* mv    = (unsigned short*)(cnt + b);               // [b][d] bf16
    unsigned short* h     = mv + (size_t)b * d;                       // [b][2d] bf16

    // normalize enc->xn and mem->yn (+norms) in one launch
    normalize_rows_bf16<<<b + m, TPB, 0, stream>>>(enc, xn, mem, yn, ynorm, b, d);

    // W1 [d][2d] -> W1T [2d][d]
    transpose_cast<<<dim3(d2 / 32, d / 32), TPB, 0, stream>>>(W1, W1T, d, d2, d2);
    // W2 [2d][outN] -> W2T [outPad][2d], zero-padded
    transpose_cast<<<dim3(outPad / 32, d2 / 32), TPB, 0, stream>>>(W2, W2T, d2, outN, outPad);

    // Z = xn * yn^T   [b][m] fp16  (cosine similarity; sparsemax is shift-invariant)
    gemm_bt<128, 2, 0, 0><<<dim3(m / 128, b / 128), TPB, 0, stream>>>(xn, yn, nullptr, Zh,
                                                                      b, d, d, m, m);
    // sparsemax + in-place compaction to (idx, w*||mem_i||) pairs
    sparsemax_compact<<<b, TPB, 0, stream>>>(Zh, ynorm, cnt, m);

    // mv = sum_support w_i * mem_i  via gather from normalized bf16 rows
    sparse_mv<<<b, TPB, 0, stream>>>((const unsigned int*)Zh, cnt, yn, mv, m / 2, d);

    // h = relu(mv * W1 + b1)   [b][2d] bf16   (BN=64 -> 512 blocks)
    gemm_bt<64, 1, 1, 1><<<dim3(d2 / 64, b / 128), TPB, 0, stream>>>(mv, W1T, b1, h,
                                                                     b, d, d, d2, d2);
    // out = h * W2 + b2   [b][outN] fp32      (BN=64 -> 256 blocks)
    gemm_bt<64, 0, 0, 1><<<dim3(outPad / 64, b / 128), TPB, 0, stream>>>(h, W2T, b2, d_out,
                                                                         b, d2, d2, outN, outN);
}